// Round 26
// baseline (108.776 us; speedup 1.0000x reference)
//
#include <hip/hip_runtime.h>
#include <hip/hip_bf16.h>

typedef float f32x4 __attribute__((ext_vector_type(4)));
typedef short short8 __attribute__((ext_vector_type(8)));
typedef short short4v __attribute__((ext_vector_type(4)));
typedef _Float16 half2v __attribute__((ext_vector_type(2)));
typedef _Float16 half8 __attribute__((ext_vector_type(8)));

static __device__ __forceinline__ short f2bf(float x) {
  union { __hip_bfloat16 b; short s; } u;
  u.b = __float2bfloat16(x);
  return u.s;
}
static __device__ __forceinline__ float bf2f(short s) {
  union { unsigned u; float f; } x;
  x.u = ((unsigned)(unsigned short)s) << 16;
  return x.f;
}
static __device__ __forceinline__ short f2h(float x) {
  union { _Float16 h; short s; } u;
  u.h = (_Float16)x;
  return u.s;
}

// ---------------------------------------------------------------------------
// f32 pre-cast: nodes|images|Wq|Wkv -> bf16 ; Wo -> f16. 8 elems/thread.
// ---------------------------------------------------------------------------
__global__ __launch_bounds__(256)
void cvt_bf16(const float* __restrict__ nodes, const float* __restrict__ images,
              const float* __restrict__ Wq, const float* __restrict__ Wkv,
              const float* __restrict__ Wo,
              short* __restrict__ nb, short* __restrict__ ib,
              short* __restrict__ wqb, short* __restrict__ wkvb,
              short* __restrict__ wob) {
  const int idx = blockIdx.x * 256 + threadIdx.x;   // 0..279039
  const float* src; short* dst; int o; bool h16 = false;
  if      (idx < 115200) { src = nodes;  dst = nb;   o = idx; }
  else if (idx < 246272) { src = images; dst = ib;   o = idx - 115200; }
  else if (idx < 254464) { src = Wq;     dst = wqb;  o = idx - 246272; }
  else if (idx < 270848) { src = Wkv;    dst = wkvb; o = idx - 254464; }
  else                   { src = Wo;     dst = wob;  o = idx - 270848; h16 = true; }
  const float4 a = ((const float4*)src)[o * 2];
  const float4 b = ((const float4*)src)[o * 2 + 1];
  short8 v;
  if (h16) {
    v[0] = f2h(a.x); v[1] = f2h(a.y); v[2] = f2h(a.z); v[3] = f2h(a.w);
    v[4] = f2h(b.x); v[5] = f2h(b.y); v[6] = f2h(b.z); v[7] = f2h(b.w);
  } else {
    v[0] = f2bf(a.x); v[1] = f2bf(a.y); v[2] = f2bf(a.z); v[3] = f2bf(a.w);
    v[4] = f2bf(b.x); v[5] = f2bf(b.y); v[6] = f2bf(b.z); v[7] = f2bf(b.w);
  }
  *(short8*)&dst[o * 8] = v;
}

// ---------------------------------------------------------------------------
// Plain projection GEMM (fallback path only).
// ---------------------------------------------------------------------------
__global__ __launch_bounds__(256, 4)
void gemm_qkv_mfma(const short* __restrict__ nb, const short* __restrict__ wqb,
                   const float* __restrict__ bq, short* __restrict__ qb,
                   const short* __restrict__ ib, const short* __restrict__ wkvb,
                   const float* __restrict__ bkv, short* __restrict__ kb,
                   short* __restrict__ vT) {
  const int t = threadIdx.x, w = t >> 6, lane = t & 63;
  const int fr = lane & 15, fk = lane >> 4;
  int bid = blockIdx.x;
  const short *A, *W; const float* bias; int M, m0, n0, kvmode;
  if (bid < 228) {
    A = nb; W = wqb; bias = bq; M = 3600; kvmode = 0;
    m0 = (bid >> 2) * 64; n0 = (bid & 3) * 64;
  } else {
    bid -= 228;
    A = ib; W = wkvb; bias = bkv; M = 4096; kvmode = 1;
    m0 = (bid >> 3) * 64; n0 = (bid & 7) * 64;
  }
  int arow = m0 + w * 16 + fr; if (arow > M - 1) arow = M - 1;
  f32x4 acc[4];
  #pragma unroll
  for (int s = 0; s < 4; ++s) acc[s] = (f32x4){0.f, 0.f, 0.f, 0.f};
  #pragma unroll 2
  for (int k0 = 0; k0 < 256; k0 += 32) {
    const short8 af = *(const short8*)&A[(size_t)arow * 256 + k0 + fk * 8];
    #pragma unroll
    for (int s = 0; s < 4; ++s) {
      const short8 wf =
          *(const short8*)&W[(size_t)(n0 + s * 16 + fr) * 256 + k0 + fk * 8];
      acc[s] = __builtin_amdgcn_mfma_f32_16x16x32_bf16(af, wf, acc[s], 0, 0, 0);
    }
  }
  #pragma unroll
  for (int s = 0; s < 4; ++s)
    #pragma unroll
    for (int r = 0; r < 4; ++r) {
      const int m = m0 + w * 16 + fk * 4 + r;
      const int n = n0 + s * 16 + fr;
      const float val = acc[s][r] + bias[n];
      if (kvmode == 0) {
        if (m < 3600) qb[(size_t)m * 256 + n] = f2bf(val);
      } else {
        if (n < 256)
          kb[(size_t)m * 256 + n] = f2bf(val);
        else
          vT[((size_t)(m >> 10) * 256 + (n - 256)) * 1024 + (m & 1023)] =
              f2bf(val);
      }
    }
}

// ---------------------------------------------------------------------------
// MERGED: cpb MLP (blocks 0..1823) + projection GEMMs (1824..2563).
// cpb chunk loop SOFTWARE-PIPELINED: sw double-buffered; MLP(c+1) is issued
// BEFORE the lgkm drain of chunk c, hiding the DS roundtrip under VALU.
// Same-wave in-order DS makes the write-after-read on sw[c&1] safe.
// (256,4): natural VGPR ~44, zero spill.
// ---------------------------------------------------------------------------
#define MLP_CHUNK(D2, BUF)                                                    \
  _Pragma("unroll")                                                           \
  for (int t4 = 0; t4 < 4; ++t4) {                                            \
    const _Float16 dxh = (_Float16)(D2)[t4].x;                                \
    const _Float16 dyh = (_Float16)(D2)[t4].y;                                \
    const half2v dx2 = (half2v)(dxh);                                         \
    const half2v dy2 = (half2v)(dyh);                                         \
    union { half2v h2[4]; half8 h8; } ua0, ua1;                               \
    _Pragma("unroll")                                                         \
    for (int p = 0; p < 4; ++p) {                                             \
      const half2v r0 = w1x2[0][p] * dx2 + w1y2[0][p] * dy2 + b12[0][p];      \
      const half2v r1 = w1x2[1][p] * dx2 + w1y2[1][p] * dy2 + b12[1][p];      \
      ua0.h2[p] = __builtin_elementwise_max(r0, zero2);                       \
      ua1.h2[p] = __builtin_elementwise_max(r1, zero2);                       \
    }                                                                         \
    f32x4 z = {0.f, 0.f, 0.f, 0.f};                                           \
    f32x4 dcp =                                                               \
        __builtin_amdgcn_mfma_f32_16x16x32_f16(ua1.h8, w2h[1], z, 0, 0, 0);   \
    dcp = __builtin_amdgcn_mfma_f32_16x16x32_f16(ua0.h8, w2h[0], dcp, 0, 0, 0);\
    const int ql = t4 >> 1;                                                   \
    const int kbase = (t4 & 1) * 16;                                          \
    if (fr < 8) {                                                             \
      short4v sv;                                                             \
      sv[0] = f2bf(dcp[0] + b2add); sv[1] = f2bf(dcp[1] + b2add);             \
      sv[2] = f2bf(dcp[2] + b2add); sv[3] = f2bf(dcp[3] + b2add);             \
      *(short4v*)&sw[(BUF)][w][fr * 2 + ql][kbase + fk * 4] = sv;             \
    }                                                                         \
    __builtin_amdgcn_sched_barrier(0);                                        \
  }

__global__ __launch_bounds__(256, 4)
void gemm_cpb(const short* __restrict__ nb, const short* __restrict__ wqb,
              const float* __restrict__ bq, short* __restrict__ qb,
              const short* __restrict__ ib, const short* __restrict__ wkvb,
              const float* __restrict__ bkv, short* __restrict__ kb,
              short* __restrict__ vT,
              const float* __restrict__ dist,
              const float* __restrict__ Wc1, const float* __restrict__ bc1,
              const float* __restrict__ Wc2, const float* __restrict__ bc2,
              short* __restrict__ cpbg) {
  __shared__ short sw[2][4][16][40];   // double-buffered; 10,240 B

  const int t = threadIdx.x, w = t >> 6, lane = t & 63;
  const int fr = lane & 15, fk = lane >> 4;

  if (blockIdx.x >= 1824) {
    // ---------------- gemm_qkv path (byte-equal logic) ----------------
    int bid = blockIdx.x - 1824;
    const short *A, *W; const float* bias; int M, m0, n0, kvmode;
    if (bid < 228) {
      A = nb; W = wqb; bias = bq; M = 3600; kvmode = 0;
      m0 = (bid >> 2) * 64; n0 = (bid & 3) * 64;
    } else {
      bid -= 228;
      A = ib; W = wkvb; bias = bkv; M = 4096; kvmode = 1;
      m0 = (bid >> 3) * 64; n0 = (bid & 7) * 64;
    }
    int arow = m0 + w * 16 + fr; if (arow > M - 1) arow = M - 1;
    f32x4 acc[4];
    #pragma unroll
    for (int s = 0; s < 4; ++s) acc[s] = (f32x4){0.f, 0.f, 0.f, 0.f};
    #pragma unroll 2
    for (int k0 = 0; k0 < 256; k0 += 32) {
      const short8 af = *(const short8*)&A[(size_t)arow * 256 + k0 + fk * 8];
      #pragma unroll
      for (int s = 0; s < 4; ++s) {
        const short8 wf =
            *(const short8*)&W[(size_t)(n0 + s * 16 + fr) * 256 + k0 + fk * 8];
        acc[s] = __builtin_amdgcn_mfma_f32_16x16x32_bf16(af, wf, acc[s], 0, 0, 0);
      }
    }
    #pragma unroll
    for (int s = 0; s < 4; ++s)
      #pragma unroll
      for (int r = 0; r < 4; ++r) {
        const int m = m0 + w * 16 + fk * 4 + r;
        const int n = n0 + s * 16 + fr;
        const float val = acc[s][r] + bias[n];
        if (kvmode == 0) {
          if (m < 3600) qb[(size_t)m * 256 + n] = f2bf(val);
        } else {
          if (n < 256)
            kb[(size_t)m * 256 + n] = f2bf(val);
          else
            vT[((size_t)(m >> 10) * 256 + (n - 256)) * 1024 + (m & 1023)] =
                f2bf(val);
        }
      }
    return;
  }

  // ---------------- cpb path (4 waves, wave-autonomous, pipelined) --------
  const int cpbid = blockIdx.x;                // 0..1823
  const int y    = cpbid / 456;                // key range 0..3
  const int rem  = cpbid - y * 456;
  const int b    = rem / 114;
  const int q0   = (rem - b * 114) * 8;        // 8 q-rows/block
  const int kb0  = y * 256;

  // layer-1 weights as packed f16 pairs: pair p covers hidden (2p, 2p+1)
  half2v w1x2[2][4], w1y2[2][4], b12[2][4];
  #pragma unroll
  for (int m = 0; m < 2; ++m)
    #pragma unroll
    for (int p = 0; p < 4; ++p) {
      const int j = m * 32 + fk * 8 + 2 * p;
      half2v hx, hy, hb;
      hx[0] = (_Float16)Wc1[2 * j];     hx[1] = (_Float16)Wc1[2 * j + 2];
      hy[0] = (_Float16)Wc1[2 * j + 1]; hy[1] = (_Float16)Wc1[2 * j + 3];
      hb[0] = (_Float16)bc1[j];         hb[1] = (_Float16)bc1[j + 1];
      w1x2[m][p] = hx; w1y2[m][p] = hy; b12[m][p] = hb;
    }
  // layer-2 weights as f16 B-frags
  half8 w2h[2];
  #pragma unroll
  for (int m = 0; m < 2; ++m)
    #pragma unroll
    for (int jj = 0; jj < 8; ++jj) {
      const float v = (fr < 8) ? Wc2[fr * 64 + m * 32 + fk * 8 + jj] : 0.f;
      w2h[m][jj] = (_Float16)v;
    }
  const float b2add = (fr < 8) ? bc2[fr] : 0.f;

  const float* dptr[4];
  #pragma unroll
  for (int t4 = 0; t4 < 4; ++t4) {
    int qg = q0 + 2 * w + (t4 >> 1); if (qg > 899) qg = 899;
    dptr[t4] = dist +
        ((size_t)(b * 900 + qg) * 1024 + kb0 + (t4 & 1) * 16 + fr) * 2;
  }

  // readback role: lane -> (head hh, q-half ql2, 16B quarter qtr)
  const int row16 = lane >> 2, qtr = lane & 3;
  const int hh = row16 >> 1, ql2 = row16 & 1;
  const int qg_out = q0 + 2 * w + ql2;         // < 912 always
  short* const gdst0 =
      cpbg + ((size_t)(b * 8 + hh) * 912 + qg_out) * 1024 + qtr * 8;

  const half2v zero2 = (half2v)((_Float16)0.f);

  // ---- prologue: MLP(0) -> buf 0; load dist chunk 1 ----
  float2 d2cur[4], d2n[4];
  #pragma unroll
  for (int t4 = 0; t4 < 4; ++t4) d2cur[t4] = *(const float2*)dptr[t4];
  MLP_CHUNK(d2cur, 0)
  #pragma unroll
  for (int t4 = 0; t4 < 4; ++t4)
    d2n[t4] = *(const float2*)(dptr[t4] + 64);

  for (int c = 0; c < 8; ++c) {
    if (c + 1 < 8) {
      // MLP(c+1) issued BEFORE chunk c's drain: hides the DS roundtrip
      MLP_CHUNK(d2n, (c + 1) & 1)
      const int c2 = (c + 2 < 8) ? c + 2 : 7;
      #pragma unroll
      for (int t4 = 0; t4 < 4; ++t4)
        d2cur[t4] = *(const float2*)(dptr[t4] + (size_t)c2 * 64);
    }
    // drain DS (chunk c writes long done; c+1's also complete here)
    asm volatile("s_waitcnt lgkmcnt(0)" ::: "memory");
    __builtin_amdgcn_sched_barrier(0);
    const short8 ov = *(const short8*)&sw[c & 1][w][row16][qtr * 8];
    *(short8*)&gdst0[kb0 + c * 32] = ov;
    #pragma unroll
    for (int t4 = 0; t4 < 4; ++t4) d2n[t4] = d2cur[t4];
  }
}

// ---------------------------------------------------------------------------
// Barrier-free KV-split flash attention (byte-identical to R15-R25 passing).
// ---------------------------------------------------------------------------
#define SCALE 0.17677669529663687f

template <int KLEN>
__global__ __launch_bounds__(512, 2)
void attn_nb(const __hip_bfloat16* __restrict__ qb,   // [4*900,256]
             const __hip_bfloat16* __restrict__ kb,   // [4*1024,256]
             const __hip_bfloat16* __restrict__ vT,   // [4,256,1024]
             const short* __restrict__ cpbg,          // [4,8,912,1024]
             const unsigned char* __restrict__ mask,  // [4,1024]
             float* __restrict__ Opart,               // [NS,4*912,256]
             float* __restrict__ msplit,              // [NS,4,8,912]
             float* __restrict__ lsplit) {
  constexpr int NCH = KLEN / 32;
  __shared__ short ps_s[8][640];       // per-wave P bf16 [q][40 pad]

  const int t    = threadIdx.x;
  const int b    = blockIdx.x / 57;
  const int q0   = (blockIdx.x % 57) * 16;
  const int sp   = blockIdx.y;
  const int kb0  = sp * KLEN;
  const int w    = t >> 6;
  const int lane = t & 63;
  const int fr   = lane & 15;
  const int fk   = lane >> 4;

  int qrow = q0 + fr; if (qrow > 899) qrow = 899;
  const short8 aq = *(const short8*)&qb[(size_t)(b * 900 + qrow) * 256 +
                                        w * 32 + fk * 8];

  const short* cpbrow[4];
  #pragma unroll
  for (int r = 0; r < 4; ++r)
    cpbrow[r] = cpbg + ((size_t)(b * 8 + w) * 912 + q0 + fk * 4 + r) * 1024 + fr;

  f32x4 of[2];
  of[0] = (f32x4){0.f, 0.f, 0.f, 0.f};
  of[1] = (f32x4){0.f, 0.f, 0.f, 0.f};
  float mreg[4], lreg[4];
  #pragma unroll
  for (int r = 0; r < 4; ++r) { mreg[r] = -1e30f; lreg[r] = 0.f; }

  short8 kf0 = *(const short8*)
      &kb[(size_t)(b * 1024 + kb0 + fr) * 256 + w * 32 + fk * 8];
  short8 kf1 = *(const short8*)
      &kb[(size_t)(b * 1024 + kb0 + 16 + fr) * 256 + w * 32 + fk * 8];
  short8 bv0 = *(const short8*)
      &vT[(size_t)(b * 256 + w * 32 + fr) * 1024 + kb0 + fk * 8];
  short8 bv1 = *(const short8*)
      &vT[(size_t)(b * 256 + w * 32 + 16 + fr) * 1024 + kb0 + fk * 8];
  float cv0c[4], cv1c[4];
  #pragma unroll
  for (int r = 0; r < 4; ++r) {
    cv0c[r] = bf2f(cpbrow[r][kb0]);
    cv1c[r] = bf2f(cpbrow[r][kb0 + 16]);
  }
  bool mk0 = mask[b * 1024 + kb0 + fr] != 0;
  bool mk1 = mask[b * 1024 + kb0 + 16 + fr] != 0;

  for (int c = 0; c < NCH; ++c) {
    const int k0 = kb0 + c * 32;

    short8 kf0n = kf0, kf1n = kf1, bv0n = bv0, bv1n = bv1;
    float cv0n[4], cv1n[4];
    bool mk0n = mk0, mk1n = mk1;
    if (c + 1 < NCH) {
      const int k1 = k0 + 32;
      kf0n = *(const short8*)
          &kb[(size_t)(b * 1024 + k1 + fr) * 256 + w * 32 + fk * 8];
      kf1n = *(const short8*)
          &kb[(size_t)(b * 1024 + k1 + 16 + fr) * 256 + w * 32 + fk * 8];
      bv0n = *(const short8*)
          &vT[(size_t)(b * 256 + w * 32 + fr) * 1024 + k1 + fk * 8];
      bv1n = *(const short8*)
          &vT[(size_t)(b * 256 + w * 32 + 16 + fr) * 1024 + k1 + fk * 8];
      #pragma unroll
      for (int r = 0; r < 4; ++r) {
        cv0n[r] = bf2f(cpbrow[r][k1]);
        cv1n[r] = bf2f(cpbrow[r][k1 + 16]);
      }
      mk0n = mask[b * 1024 + k1 + fr] != 0;
      mk1n = mask[b * 1024 + k1 + 16 + fr] != 0;
    } else {
      #pragma unroll
      for (int r = 0; r < 4; ++r) { cv0n[r] = cv0c[r]; cv1n[r] = cv1c[r]; }
    }

    f32x4 z = {0.f, 0.f, 0.f, 0.f};
    __builtin_amdgcn_s_setprio(1);
    const f32x4 sc0 = __builtin_amdgcn_mfma_f32_16x16x32_bf16(aq, kf0, z, 0, 0, 0);
    const f32x4 sc1 = __builtin_amdgcn_mfma_f32_16x16x32_bf16(aq, kf1, z, 0, 0, 0);
    __builtin_amdgcn_s_setprio(0);

    float s0v[4], s1v[4];
    bool need = false;
    #pragma unroll
    for (int r = 0; r < 4; ++r) {
      s0v[r] = mk0 ? -1e30f : fmaf(sc0[r], SCALE, cv0c[r]);
      s1v[r] = mk1 ? -1e30f : fmaf(sc1[r], SCALE, cv1c[r]);
      need = need || (fmaxf(s0v[r], s1v[r]) > mreg[r] + 8.f);
    }
    if (__any((int)need)) {
      #pragma unroll
      for (int r = 0; r < 4; ++r) {
        float mx = fmaxf(s0v[r], s1v[r]);
        mx = fmaxf(mx, __shfl_xor(mx, 1));
        mx = fmaxf(mx, __shfl_xor(mx, 2));
        mx = fmaxf(mx, __shfl_xor(mx, 4));
        mx = fmaxf(mx, __shfl_xor(mx, 8));
        const float mnew = fmaxf(mreg[r], mx);
        const float al = __expf(mreg[r] - mnew);
        of[0][r] *= al;
        of[1][r] *= al;
        lreg[r] *= al;
        mreg[r] = mnew;
      }
    }
    #pragma unroll
    for (int r = 0; r < 4; ++r) {
      const int q = fk * 4 + r;
      const float p0 = __expf(s0v[r] - mreg[r]);
      const float p1 = __expf(s1v[r] - mreg[r]);
      ps_s[w][q * 40 + fr]      = f2bf(p0);
      ps_s[w][q * 40 + 16 + fr] = f2bf(p1);
      lreg[r] += p0 + p1;
    }

    asm volatile("s_waitcnt lgkmcnt(0)" ::: "memory");
    __builtin_amdgcn_sched_barrier(0);

    const short8 ap = *(const short8*)&ps_s[w][fr * 40 + fk * 8];
    __builtin_amdgcn_s_setprio(1);
    of[0] = __builtin_amdgcn_mfma_f32_16x16x32_bf16(ap, bv0, of[0], 0, 0, 0);
    of[1] = __builtin_amdgcn_mfma_f32_16x16x32_bf16(ap, bv1, of[1], 0, 0, 0);
    __builtin_amdgcn_s_setprio(0);

    kf0 = kf0n; kf1 = kf1n; bv0 = bv0n; bv1 = bv1n;
    mk0 = mk0n; mk1 = mk1n;
    #pragma unroll
    for (int r = 0; r < 4; ++r) { cv0c[r] = cv0n[r]; cv1c[r] = cv1n[r]; }
  }

  #pragma unroll
  for (int r = 0; r < 4; ++r) {
    lreg[r] += __shfl_xor(lreg[r], 1);
    lreg[r] += __shfl_xor(lreg[r], 2);
    lreg[r] += __shfl_xor(lreg[r], 4);
    lreg[r] += __shfl_xor(lreg[r], 8);
  }
  #pragma unroll
  for (int s = 0; s < 2; ++s)
    #pragma unroll
    for (int r = 0; r < 4; ++r) {
      const int qg = q0 + fk * 4 + r;
      Opart[((size_t)sp * 3648 + b * 912 + qg) * 256 + w * 32 + s * 16 + fr] =
          of[s][r];
    }
  if (fr == 0) {
    #pragma unroll
    for (int r = 0; r < 4; ++r) {
      const int qg = q0 + fk * 4 + r;
      msplit[((sp * 4 + b) * 8 + w) * 912 + qg] = mreg[r];
      lsplit[((sp * 4 + b) * 8 + w) * 912 + qg] = lreg[r];
    }
  }
}

// ---------------------------------------------------------------------------
// FALLBACK (ws too small for cpbg): fused attn (bf16 cpb LDS, 1 barrier).
// ---------------------------------------------------------------------------
#define BAR()                                              \
  asm volatile("s_waitcnt lgkmcnt(0)" ::: "memory");       \
  __builtin_amdgcn_s_barrier();                            \
  asm volatile("" ::: "memory")

template <int KLEN>
__global__ __launch_bounds__(512, 2)
void attn_part(const __hip_bfloat16* __restrict__ qb,
               const __hip_bfloat16* __restrict__ kb,
               const __hip_bfloat16* __restrict__ vT,
               const float* __restrict__ dist,
               const unsigned char* __restrict__ mask,
               const float* __restrict__ Wc1, const float* __restrict__ bc1,
               const float* __restrict__ Wc2, const float* __restrict__ bc2,
               float* __restrict__ Opart, float* __restrict__ msplit,
               float* __restrict__ lsplit) {
  constexpr int NCH = KLEN / 32;
  __shared__ short cpb_s[2][8 * 552];
  __shared__ short ps_s[8][640];

  const int t    = threadIdx.x;
  const int b    = blockIdx.x / 57;
  const int q0   = (blockIdx.x % 57) * 16;
  const int sp   = blockIdx.y;
  const int kb0  = sp * KLEN;
  const int w    = t >> 6;
  const int lane = t & 63;
  const int fr   = lane & 15;
  const int fk   = lane >> 4;

  float w1x[2][8], w1y[2][8], w1b[2][8];
  #pragma unroll
  for (int m = 0; m < 2; ++m)
    #pragma unroll
    for (int jj = 0; jj < 8; ++jj) {
      const int j = m * 32 + fk * 8 + jj;
      w1x[m][jj] = Wc1[2 * j];
      w1y[m][jj] = Wc1[2 * j + 1];
      w1b[m][jj] = bc1[j];
    }
  short8 w2f[2];
  #pragma unroll
  for (int m = 0; m < 2; ++m)
    #pragma unroll
    for (int jj = 0; jj < 8; ++jj) {
      const float v = (fr < 8) ? Wc2[fr * 64 + m * 32 + fk * 8 + jj] : 0.f;
      w2f[m][jj] = f2bf(v);
    }
  const float b2add = (fr < 8) ? bc2[fr] : 0.f;

  int qrow = q0 + fr; if (qrow > 899) qrow = 899;
  const short8 aq = *(const short8*)&qb[(size_t)(b * 900 + qrow) * 256 +
                                        w * 32 + fk * 8];

  const float* dptr[4];
  float2 d2cur[4];
  #pragma unroll
  for (int t4 = 0; t4 < 4; ++t4) {
    int qg = q0 + 2 * w + (t4 >> 1); if (qg > 899) qg = 899;
    dptr[t4] = dist +
        ((size_t)(b * 900 + qg) * 1024 + kb0 + (t4 & 1) * 16 + fr) * 2;
    d2cur[t4] = *(const float2*)dptr[t4];
  }

  f32x4 of[2];
  of[0] = (f32x4){0.f, 0.f, 0.f, 0.f};
  of[1] = (f32x4){0.f, 0.f, 0.f, 0.f};
  float mreg[4], lreg[4];
  #pragma unroll
  for (int r = 0; r < 4; ++r) { mreg[r] = -1e30f; lreg[r] = 0.f; }

  for (int c = 0; c < NCH; ++c) {
    const int k0 = kb0 + c * 32;
    const int cn = (c < NCH - 1) ? c + 1 : c;
    short* cpb_c = cpb_s[c & 1];

    float2 d2n[4];
    #pragma unroll
    for (int t4 = 0; t4 < 4; ++t4)
      d2n[t4] = *(const float2*)(dptr[t4] + (size_t)cn * 64);
    const short8 kf0 = *(const short8*)
        &kb[(size_t)(b * 1024 + k0 + fr) * 256 + w * 32 + fk * 8];
    const short8 kf1 = *(const short8*)
        &kb[(size_t)(b * 1024 + k0 + 16 + fr) * 256 + w * 32 + fk * 8];
    const short8 bv0 = *(const short8*)
        &vT[(size_t)(b * 256 + w * 32 + fr) * 1024 + k0 + fk * 8];
    const short8 bv1 = *(const short8*)
        &vT[(size_t)(b * 256 + w * 32 + 16 + fr) * 1024 + k0 + fk * 8];
    const bool mk0 = mask[b * 1024 + k0 + fr] != 0;
    const bool mk1 = mask[b * 1024 + k0 + 16 + fr] != 0;

    #pragma unroll
    for (int t4 = 0; t4 < 4; ++t4) {
      const float dx = d2cur[t4].x, dy = d2cur[t4].y;
      short8 a0, a1;
      #pragma unroll
      for (int jj = 0; jj < 8; ++jj) {
        const float h0 =
            fmaxf(fmaf(w1x[0][jj], dx, fmaf(w1y[0][jj], dy, w1b[0][jj])), 0.f);
        const float h1 =
            fmaxf(fmaf(w1x[1][jj], dx, fmaf(w1y[1][jj], dy, w1b[1][jj])), 0.f);
        a0[jj] = f2bf(h0);
        a1[jj] = f2bf(h1);
      }
      f32x4 z = {0.f, 0.f, 0.f, 0.f};
      f32x4 dcp = __builtin_amdgcn_mfma_f32_16x16x32_bf16(a1, w2f[1], z, 0, 0, 0);
      dcp = __builtin_amdgcn_mfma_f32_16x16x32_bf16(a0, w2f[0], dcp, 0, 0, 0);
      const int qloc = 2 * w + (t4 >> 1);
      const int kbase = (t4 & 1) * 16;
      if (fr < 8) {
        #pragma unroll
        for (int rr = 0; rr < 4; ++rr)
          cpb_c[fr * 552 + qloc * 34 + kbase + fk * 4 + rr] =
              f2bf(dcp[rr] + b2add);
      }
      __builtin_amdgcn_sched_barrier(0);
    }

    BAR();

    f32x4 z = {0.f, 0.f, 0.f, 0.f};
    __builtin_amdgcn_s_setprio(1);
    const f32x4 sc0 = __builtin_amdgcn_mfma_f32_16x16x32_bf16(aq, kf0, z, 0, 0, 0);
    const f32x4 sc1 = __builtin_amdgcn_mfma_f32_16x16x32_bf16(aq, kf1, z, 0, 0, 0);
    __builtin_amdgcn_s_setprio(0);

    float s0v[4], s1v[4];
    bool need = false;
    #pragma unroll
    for (int r = 0; r < 4; ++r) {
      const int q = fk * 4 + r;
      const float cv0 = bf2f(cpb_c[w * 552 + q * 34 + fr]);
      const float cv1 = bf2f(cpb_c[w * 552 + q * 34 + 16 + fr]);
      s0v[r] = mk0 ? -1e30f : fmaf(sc0[r], SCALE, cv0);
      s1v[r] = mk1 ? -1e30f : fmaf(sc1[r], SCALE, cv1);
      need = need || (fmaxf(s0v[r], s1v[r]) > mreg[r] + 8.f);
    }
    if (__any((int)need)) {
      #pragma unroll
      for (int r = 0; r < 4; ++r) {
        float mx = fmaxf(s0v[r], s1v[r]);
        mx = fmaxf(mx, __shfl_xor(mx, 1));
        mx = fmaxf(mx, __shfl_xor(mx, 2));
        mx = fmaxf(mx, __shfl_xor(mx, 4));
        mx = fmaxf(mx, __shfl_xor(mx, 8));
        const float mnew = fmaxf(mreg[r], mx);
        const float al = __expf(mreg[r] - mnew);
        of[0][r] *= al;
        of[1][r] *= al;
        lreg[r] *= al;
        mreg[r] = mnew;
      }
    }
    #pragma unroll
    for (int r = 0; r < 4; ++r) {
      const int q = fk * 4 + r;
      const float p0 = __expf(s0v[r] - mreg[r]);
      const float p1 = __expf(s1v[r] - mreg[r]);
      ps_s[w][q * 40 + fr]      = f2bf(p0);
      ps_s[w][q * 40 + 16 + fr] = f2bf(p1);
      lreg[r] += p0 + p1;
    }

    asm volatile("s_waitcnt lgkmcnt(0)" ::: "memory");
    __builtin_amdgcn_sched_barrier(0);

    const short8 ap = *(const short8*)&ps_s[w][fr * 40 + fk * 8];
    __builtin_amdgcn_s_setprio(1);
    of[0] = __builtin_amdgcn_mfma_f32_16x16x32_bf16(ap, bv0, of[0], 0, 0, 0);
    of[1] = __builtin_amdgcn_mfma_f32_16x16x32_bf16(ap, bv1, of[1], 0, 0, 0);
    __builtin_amdgcn_s_setprio(0);

    #pragma unroll
    for (int t4 = 0; t4 < 4; ++t4) d2cur[t4] = d2n[t4];
  }

  #pragma unroll
  for (int r = 0; r < 4; ++r) {
    lreg[r] += __shfl_xor(lreg[r], 1);
    lreg[r] += __shfl_xor(lreg[r], 2);
    lreg[r] += __shfl_xor(lreg[r], 4);
    lreg[r] += __shfl_xor(lreg[r], 8);
  }
  #pragma unroll
  for (int s = 0; s < 2; ++s)
    #pragma unroll
    for (int r = 0; r < 4; ++r) {
      const int qg = q0 + fk * 4 + r;
      Opart[((size_t)sp * 3648 + b * 912 + qg) * 256 + w * 32 + s * 16 + fr] =
          of[s][r];
    }
  if (fr == 0) {
    #pragma unroll
    for (int r = 0; r < 4; ++r) {
      const int qg = q0 + fk * 4 + r;
      msplit[((sp * 4 + b) * 8 + w) * 912 + qg] = mreg[r];
      lsplit[((sp * 4 + b) * 8 + w) * 912 + qg] = lreg[r];
    }
  }
}

// ---------------------------------------------------------------------------
// Fused combine + out-proj (f16 MFMA; wob pre-cast to f16).
// ---------------------------------------------------------------------------
template <int NS>
__global__ __launch_bounds__(256, 4)
void gemm_out_combine(const float* __restrict__ Opart,
                      const float* __restrict__ msplit,
                      const float* __restrict__ lsplit,
                      const short* __restrict__ wob, const float* __restrict__ bo,
                      float* __restrict__ out) {
  const int t = threadIdx.x, w = t >> 6, lane = t & 63;
  const int fr = lane & 15, fk = lane >> 4;
  const int m0 = (blockIdx.x >> 2) * 64, n0 = (blockIdx.x & 3) * 64;
  int arow = m0 + w * 16 + fr; if (arow > 3599) arow = 3599;
  const int b = arow / 900, q = arow - b * 900;
  const int row912 = b * 912 + q;
  f32x4 acc[4];
  #pragma unroll
  for (int s = 0; s < 4; ++s) acc[s] = (f32x4){0.f, 0.f, 0.f, 0.f};
  #pragma unroll 2
  for (int k0 = 0; k0 < 256; k0 += 32) {
    const int h = k0 >> 5;
    float mv[NS], M = -1e30f;
    #pragma unroll
    for (int s = 0; s < NS; ++s) {
      mv[s] = msplit[((s * 4 + b) * 8 + h) * 912 + q];
      M = fmaxf(M, mv[s]);
    }
    float L = 0.f, wgt[NS];
    #pragma unroll
    for (int s = 0; s < NS; ++s) {
      wgt[s] = __expf(mv[s] - M);
      L = fmaf(lsplit[((s * 4 + b) * 8 + h) * 912 + q], wgt[s], L);
    }
    const float rL = 1.f / L;
    float av[8];
    #pragma unroll
    for (int j = 0; j < 8; ++j) av[j] = 0.f;
    #pragma unroll
    for (int s = 0; s < NS; ++s) {
      const float* op = &Opart[((size_t)s * 3648 + row912) * 256 + k0 + fk * 8];
      const float4 o0 = *(const float4*)op;
      const float4 o1 = *(const float4*)(op + 4);
      const float ws = wgt[s] * rL;
      av[0] = fmaf(o0.x, ws, av[0]); av[1] = fmaf(o0.y, ws, av[1]);
      av[2] = fmaf(o0.z, ws, av[2]); av[3] = fmaf(o0.w, ws, av[3]);
      av[4] = fmaf(o1.x, ws, av[4]); av[5] = fmaf(o1.y, ws, av[5]);
      av[6] = fmaf(o1.z, ws, av[6]); av[7] = fmaf(o1.w, ws, av[7]);
    }
    half8 af;
    #pragma unroll
    for (int j = 0; j < 8; ++j) af[j] = (_Float16)av[j];
    #pragma unroll
    for (int s = 0; s < 4; ++s) {
      union { short8 s8; half8 h8; } wf;
      wf.s8 = *(const short8*)&wob[(size_t)(n0 + s * 16 + fr) * 256 + k0 + fk * 8];
      acc[s] = __builtin_amdgcn_mfma_f32_16x16x32_f16(af, wf.h8, acc[s], 0, 0, 0);
    }
  }
  #pragma unroll
  for (int s = 0; s < 4; ++s)
    #pragma unroll
    for (int r = 0; r < 4; ++r) {
      const int m = m0 + w * 16 + fk * 4 + r;
      const int n = n0 + s * 16 + fr;
      if (m < 3600) out[(size_t)m * 256 + n] = acc[s][r] + bo[n];
    }
}

// ---------------------------------------------------------------------------
extern "C" void kernel_launch(void* const* d_in, const int* in_sizes, int n_in,
                              void* d_out, int out_size, void* d_ws, size_t ws_size,
                              hipStream_t stream) {
  const float* nodes  = (const float*)d_in[0];
  const float* images = (const float*)d_in[1];
  const unsigned char* mask = (const unsigned char*)d_in[2];
  const float* dist   = (const float*)d_in[3];
  const float* Wq     = (const float*)d_in[4];
  const float* bq     = (const float*)d_in[5];
  const float* Wkv    = (const float*)d_in[6];
  const float* bkv    = (const float*)d_in[7];
  const float* Wc1    = (const float*)d_in[8];
  const float* bc1    = (const float*)d_in[9];
  const float* Wc2    = (const float*)d_in[10];
  const float* bc2    = (const float*)d_in[11];
  const float* Wo     = (const float*)d_in[12];
  const float* bo     = (const float*)d_in[13];
  float* out = (float*)d_out;

  char* wp = (char*)d_ws;
  short* qb = (short*)wp;                       // 1,843,200
  short* kb = (short*)(wp + 1843200);           // 2,097,152
  short* vT = (short*)(wp + 3940352);           // 2,097,152
  char*  S  = wp + 6037504;
  short* nb   = (short*)S;
  short* ib   = (short*)(S + 1843200);
  short* wqb  = (short*)(S + 3940352);
  short* wkvb = (short*)(S + 4071424);          // phase1 ends 4,333,568
  float* Opart = (float*)S;

  const size_t opart_b = (size_t)3648 * 256 * 4;      // 3,735,552
  const size_t ml_b    = (size_t)4 * 8 * 912 * 4;     //   116,736
  const size_t s2_2    = 2 * (opart_b + 2 * ml_b);    // 7,938,048
  const size_t cpbg_sz = (size_t)4 * 8 * 912 * 1024 * 2;  // 59,768,832
  const size_t need_big = 6037504u + s2_2 + cpbg_sz + 131072u;
  const size_t need2    = 6037504u + s2_2 + 131072u;

  if (ws_size >= need_big) {
    short* cpbg = (short*)(S + s2_2);
    short* wob  = (short*)(S + s2_2 + cpbg_sz);
    float* msplit = Opart + (size_t)2 * 3648 * 256;
    float* lsplit = msplit + (size_t)2 * 4 * 8 * 912;
    cvt_bf16<<<1090, 256, 0, stream>>>(nodes, images, Wq, Wkv, Wo,
                                       nb, ib, wqb, wkvb, wob);
    gemm_cpb<<<2564, 256, 0, stream>>>(nb, wqb, bq, qb, ib, wkvb, bkv, kb, vT,
                                       dist, Wc1, bc1, Wc2, bc2, cpbg);
    attn_nb<512><<<dim3(228, 2), 512, 0, stream>>>(
        (const __hip_bfloat16*)qb, (const __hip_bfloat16*)kb,
        (const __hip_bfloat16*)vT, cpbg, mask, Opart, msplit, lsplit);
    gemm_out_combine<2><<<228, 256, 0, stream>>>(Opart, msplit, lsplit,
                                                 wob, bo, out);
  } else {
    int nsplit = (ws_size >= need2) ? 2 : 1;
    const size_t Ssize = (nsplit == 2) ? s2_2 : 4333568u;
    short* wob = (short*)(S + Ssize);
    float* msplit = Opart + (size_t)nsplit * 3648 * 256;
    float* lsplit = msplit + (size_t)nsplit * 4 * 8 * 912;
    cvt_bf16<<<1090, 256, 0, stream>>>(nodes, images, Wq, Wkv, Wo,
                                       nb, ib, wqb, wkvb, wob);
    gemm_qkv_mfma<<<740, 256, 0, stream>>>(nb, wqb, bq, qb, ib, wkvb, bkv,
                                           kb, vT);
    if (nsplit == 2) {
      attn_part<512><<<dim3(228, 2), 512, 0, stream>>>(
          (const __hip_bfloat16*)qb, (const __hip_bfloat16*)kb,
          (const __hip_bfloat16*)vT, dist, mask, Wc1, bc1, Wc2, bc2,
          Opart, msplit, lsplit);
      gemm_out_combine<2><<<228, 256, 0, stream>>>(Opart, msplit, lsplit,
                                                   wob, bo, out);
    } else {
      attn_part<1024><<<dim3(228, 1), 512, 0, stream>>>(
          (const __hip_bfloat16*)qb, (const __hip_bfloat16*)kb,
          (const __hip_bfloat16*)vT, dist, mask, Wc1, bc1, Wc2, bc2,
          Opart, msplit, lsplit);
      gemm_out_combine<1><<<228, 256, 0, stream>>>(Opart, msplit, lsplit,
                                                   wob, bo, out);
    }
  }
}

// Round 27
// 107.121 us; speedup vs baseline: 1.0154x; 1.0154x over previous
//
#include <hip/hip_runtime.h>
#include <hip/hip_bf16.h>

typedef float f32x4 __attribute__((ext_vector_type(4)));
typedef short short8 __attribute__((ext_vector_type(8)));
typedef short short4v __attribute__((ext_vector_type(4)));
typedef _Float16 half2v __attribute__((ext_vector_type(2)));
typedef _Float16 half8 __attribute__((ext_vector_type(8)));

static __device__ __forceinline__ short f2bf(float x) {
  union { __hip_bfloat16 b; short s; } u;
  u.b = __float2bfloat16(x);
  return u.s;
}
static __device__ __forceinline__ float bf2f(short s) {
  union { unsigned u; float f; } x;
  x.u = ((unsigned)(unsigned short)s) << 16;
  return x.f;
}
static __device__ __forceinline__ short f2h(float x) {
  union { _Float16 h; short s; } u;
  u.h = (_Float16)x;
  return u.s;
}

// ---------------------------------------------------------------------------
// f32 pre-cast: nodes|images|Wq|Wkv -> bf16 ; Wo -> f16. 8 elems/thread.
// ---------------------------------------------------------------------------
__global__ __launch_bounds__(256)
void cvt_bf16(const float* __restrict__ nodes, const float* __restrict__ images,
              const float* __restrict__ Wq, const float* __restrict__ Wkv,
              const float* __restrict__ Wo,
              short* __restrict__ nb, short* __restrict__ ib,
              short* __restrict__ wqb, short* __restrict__ wkvb,
              short* __restrict__ wob) {
  const int idx = blockIdx.x * 256 + threadIdx.x;   // 0..279039
  const float* src; short* dst; int o; bool h16 = false;
  if      (idx < 115200) { src = nodes;  dst = nb;   o = idx; }
  else if (idx < 246272) { src = images; dst = ib;   o = idx - 115200; }
  else if (idx < 254464) { src = Wq;     dst = wqb;  o = idx - 246272; }
  else if (idx < 270848) { src = Wkv;    dst = wkvb; o = idx - 254464; }
  else                   { src = Wo;     dst = wob;  o = idx - 270848; h16 = true; }
  const float4 a = ((const float4*)src)[o * 2];
  const float4 b = ((const float4*)src)[o * 2 + 1];
  short8 v;
  if (h16) {
    v[0] = f2h(a.x); v[1] = f2h(a.y); v[2] = f2h(a.z); v[3] = f2h(a.w);
    v[4] = f2h(b.x); v[5] = f2h(b.y); v[6] = f2h(b.z); v[7] = f2h(b.w);
  } else {
    v[0] = f2bf(a.x); v[1] = f2bf(a.y); v[2] = f2bf(a.z); v[3] = f2bf(a.w);
    v[4] = f2bf(b.x); v[5] = f2bf(b.y); v[6] = f2bf(b.z); v[7] = f2bf(b.w);
  }
  *(short8*)&dst[o * 8] = v;
}

// ---------------------------------------------------------------------------
// Plain projection GEMM (fallback path only).
// ---------------------------------------------------------------------------
__global__ __launch_bounds__(256, 4)
void gemm_qkv_mfma(const short* __restrict__ nb, const short* __restrict__ wqb,
                   const float* __restrict__ bq, short* __restrict__ qb,
                   const short* __restrict__ ib, const short* __restrict__ wkvb,
                   const float* __restrict__ bkv, short* __restrict__ kb,
                   short* __restrict__ vT) {
  const int t = threadIdx.x, w = t >> 6, lane = t & 63;
  const int fr = lane & 15, fk = lane >> 4;
  int bid = blockIdx.x;
  const short *A, *W; const float* bias; int M, m0, n0, kvmode;
  if (bid < 228) {
    A = nb; W = wqb; bias = bq; M = 3600; kvmode = 0;
    m0 = (bid >> 2) * 64; n0 = (bid & 3) * 64;
  } else {
    bid -= 228;
    A = ib; W = wkvb; bias = bkv; M = 4096; kvmode = 1;
    m0 = (bid >> 3) * 64; n0 = (bid & 7) * 64;
  }
  int arow = m0 + w * 16 + fr; if (arow > M - 1) arow = M - 1;
  f32x4 acc[4];
  #pragma unroll
  for (int s = 0; s < 4; ++s) acc[s] = (f32x4){0.f, 0.f, 0.f, 0.f};
  #pragma unroll 2
  for (int k0 = 0; k0 < 256; k0 += 32) {
    const short8 af = *(const short8*)&A[(size_t)arow * 256 + k0 + fk * 8];
    #pragma unroll
    for (int s = 0; s < 4; ++s) {
      const short8 wf =
          *(const short8*)&W[(size_t)(n0 + s * 16 + fr) * 256 + k0 + fk * 8];
      acc[s] = __builtin_amdgcn_mfma_f32_16x16x32_bf16(af, wf, acc[s], 0, 0, 0);
    }
  }
  #pragma unroll
  for (int s = 0; s < 4; ++s)
    #pragma unroll
    for (int r = 0; r < 4; ++r) {
      const int m = m0 + w * 16 + fk * 4 + r;
      const int n = n0 + s * 16 + fr;
      const float val = acc[s][r] + bias[n];
      if (kvmode == 0) {
        if (m < 3600) qb[(size_t)m * 256 + n] = f2bf(val);
      } else {
        if (n < 256)
          kb[(size_t)m * 256 + n] = f2bf(val);
        else
          vT[((size_t)(m >> 10) * 256 + (n - 256)) * 1024 + (m & 1023)] =
              f2bf(val);
      }
    }
}

// ---------------------------------------------------------------------------
// MERGED: cpb MLP (blocks 0..1823, first: long pole) + projection GEMMs
// (blocks 1824..2563, tail-fill). cpb layer-1 packed f16 (v_pk_fma_f16).
// (256,4): proven optimum — natural VGPR 44, zero spill; higher bounds
// squeeze the allocator below 44 and spill (R23: cap64->32, R24: cap85->40).
// ---------------------------------------------------------------------------
__global__ __launch_bounds__(256, 4)
void gemm_cpb(const short* __restrict__ nb, const short* __restrict__ wqb,
              const float* __restrict__ bq, short* __restrict__ qb,
              const short* __restrict__ ib, const short* __restrict__ wkvb,
              const float* __restrict__ bkv, short* __restrict__ kb,
              short* __restrict__ vT,
              const float* __restrict__ dist,
              const float* __restrict__ Wc1, const float* __restrict__ bc1,
              const float* __restrict__ Wc2, const float* __restrict__ bc2,
              short* __restrict__ cpbg) {
  __shared__ short sw[4][16][40];      // cpb path only; 5,120 B

  const int t = threadIdx.x, w = t >> 6, lane = t & 63;
  const int fr = lane & 15, fk = lane >> 4;

  if (blockIdx.x >= 1824) {
    // ---------------- gemm_qkv path (byte-equal logic) ----------------
    int bid = blockIdx.x - 1824;
    const short *A, *W; const float* bias; int M, m0, n0, kvmode;
    if (bid < 228) {
      A = nb; W = wqb; bias = bq; M = 3600; kvmode = 0;
      m0 = (bid >> 2) * 64; n0 = (bid & 3) * 64;
    } else {
      bid -= 228;
      A = ib; W = wkvb; bias = bkv; M = 4096; kvmode = 1;
      m0 = (bid >> 3) * 64; n0 = (bid & 7) * 64;
    }
    int arow = m0 + w * 16 + fr; if (arow > M - 1) arow = M - 1;
    f32x4 acc[4];
    #pragma unroll
    for (int s = 0; s < 4; ++s) acc[s] = (f32x4){0.f, 0.f, 0.f, 0.f};
    #pragma unroll 2
    for (int k0 = 0; k0 < 256; k0 += 32) {
      const short8 af = *(const short8*)&A[(size_t)arow * 256 + k0 + fk * 8];
      #pragma unroll
      for (int s = 0; s < 4; ++s) {
        const short8 wf =
            *(const short8*)&W[(size_t)(n0 + s * 16 + fr) * 256 + k0 + fk * 8];
        acc[s] = __builtin_amdgcn_mfma_f32_16x16x32_bf16(af, wf, acc[s], 0, 0, 0);
      }
    }
    #pragma unroll
    for (int s = 0; s < 4; ++s)
      #pragma unroll
      for (int r = 0; r < 4; ++r) {
        const int m = m0 + w * 16 + fk * 4 + r;
        const int n = n0 + s * 16 + fr;
        const float val = acc[s][r] + bias[n];
        if (kvmode == 0) {
          if (m < 3600) qb[(size_t)m * 256 + n] = f2bf(val);
        } else {
          if (n < 256)
            kb[(size_t)m * 256 + n] = f2bf(val);
          else
            vT[((size_t)(m >> 10) * 256 + (n - 256)) * 1024 + (m & 1023)] =
                f2bf(val);
        }
      }
    return;
  }

  // ---------------- cpb path (4 waves, wave-autonomous) ----------------
  const int cpbid = blockIdx.x;                // 0..1823
  const int y    = cpbid / 456;                // key range 0..3
  const int rem  = cpbid - y * 456;
  const int b    = rem / 114;
  const int q0   = (rem - b * 114) * 8;        // 8 q-rows/block
  const int kb0  = y * 256;

  // layer-1 weights as packed f16 pairs: pair p covers hidden (2p, 2p+1)
  half2v w1x2[2][4], w1y2[2][4], b12[2][4];
  #pragma unroll
  for (int m = 0; m < 2; ++m)
    #pragma unroll
    for (int p = 0; p < 4; ++p) {
      const int j = m * 32 + fk * 8 + 2 * p;
      half2v hx, hy, hb;
      hx[0] = (_Float16)Wc1[2 * j];     hx[1] = (_Float16)Wc1[2 * j + 2];
      hy[0] = (_Float16)Wc1[2 * j + 1]; hy[1] = (_Float16)Wc1[2 * j + 3];
      hb[0] = (_Float16)bc1[j];         hb[1] = (_Float16)bc1[j + 1];
      w1x2[m][p] = hx; w1y2[m][p] = hy; b12[m][p] = hb;
    }
  // layer-2 weights as f16 B-frags
  half8 w2h[2];
  #pragma unroll
  for (int m = 0; m < 2; ++m)
    #pragma unroll
    for (int jj = 0; jj < 8; ++jj) {
      const float v = (fr < 8) ? Wc2[fr * 64 + m * 32 + fk * 8 + jj] : 0.f;
      w2h[m][jj] = (_Float16)v;
    }
  const float b2add = (fr < 8) ? bc2[fr] : 0.f;

  const float* dptr[4];
  float2 d2cur[4];
  #pragma unroll
  for (int t4 = 0; t4 < 4; ++t4) {
    int qg = q0 + 2 * w + (t4 >> 1); if (qg > 899) qg = 899;
    dptr[t4] = dist +
        ((size_t)(b * 900 + qg) * 1024 + kb0 + (t4 & 1) * 16 + fr) * 2;
    d2cur[t4] = *(const float2*)dptr[t4];
  }

  // readback role: lane -> (head hh, q-half ql2, 16B quarter qtr)
  const int row16 = lane >> 2, qtr = lane & 3;
  const int hh = row16 >> 1, ql2 = row16 & 1;
  const int qg_out = q0 + 2 * w + ql2;         // < 912 always
  short* const gdst0 =
      cpbg + ((size_t)(b * 8 + hh) * 912 + qg_out) * 1024 + qtr * 8;

  const half2v zero2 = (half2v)((_Float16)0.f);

  for (int c = 0; c < 8; ++c) {
    const int k0 = kb0 + c * 32;
    const int cn = (c < 7) ? c + 1 : c;
    float2 d2n[4];
    #pragma unroll
    for (int t4 = 0; t4 < 4; ++t4)
      d2n[t4] = *(const float2*)(dptr[t4] + (size_t)cn * 64);

    #pragma unroll
    for (int t4 = 0; t4 < 4; ++t4) {
      const _Float16 dxh = (_Float16)d2cur[t4].x;
      const _Float16 dyh = (_Float16)d2cur[t4].y;
      const half2v dx2 = (half2v)(dxh);
      const half2v dy2 = (half2v)(dyh);
      union { half2v h2[4]; half8 h8; } ua0, ua1;
      #pragma unroll
      for (int p = 0; p < 4; ++p) {
        const half2v r0 = w1x2[0][p] * dx2 + w1y2[0][p] * dy2 + b12[0][p];
        const half2v r1 = w1x2[1][p] * dx2 + w1y2[1][p] * dy2 + b12[1][p];
        ua0.h2[p] = __builtin_elementwise_max(r0, zero2);
        ua1.h2[p] = __builtin_elementwise_max(r1, zero2);
      }
      f32x4 z = {0.f, 0.f, 0.f, 0.f};
      f32x4 dcp =
          __builtin_amdgcn_mfma_f32_16x16x32_f16(ua1.h8, w2h[1], z, 0, 0, 0);
      dcp = __builtin_amdgcn_mfma_f32_16x16x32_f16(ua0.h8, w2h[0], dcp, 0, 0, 0);
      const int ql = t4 >> 1;                  // wave-local q (0/1)
      const int kbase = (t4 & 1) * 16;
      if (fr < 8) {
        short4v sv;
        sv[0] = f2bf(dcp[0] + b2add); sv[1] = f2bf(dcp[1] + b2add);
        sv[2] = f2bf(dcp[2] + b2add); sv[3] = f2bf(dcp[3] + b2add);
        *(short4v*)&sw[w][fr * 2 + ql][kbase + fk * 4] = sv;
      }
      __builtin_amdgcn_sched_barrier(0);
    }

    // same-wave LDS write -> read (in-order DS), then coalesced 16B stores
    asm volatile("s_waitcnt lgkmcnt(0)" ::: "memory");
    __builtin_amdgcn_sched_barrier(0);
    const short8 ov = *(const short8*)&sw[w][row16][qtr * 8];
    *(short8*)&gdst0[k0] = ov;

    #pragma unroll
    for (int t4 = 0; t4 < 4; ++t4) d2cur[t4] = d2n[t4];
  }
}

// ---------------------------------------------------------------------------
// Barrier-free KV-split flash attention (byte-identical to R15-R25 passing).
// ---------------------------------------------------------------------------
#define SCALE 0.17677669529663687f

template <int KLEN>
__global__ __launch_bounds__(512, 2)
void attn_nb(const __hip_bfloat16* __restrict__ qb,   // [4*900,256]
             const __hip_bfloat16* __restrict__ kb,   // [4*1024,256]
             const __hip_bfloat16* __restrict__ vT,   // [4,256,1024]
             const short* __restrict__ cpbg,          // [4,8,912,1024]
             const unsigned char* __restrict__ mask,  // [4,1024]
             float* __restrict__ Opart,               // [NS,4*912,256]
             float* __restrict__ msplit,              // [NS,4,8,912]
             float* __restrict__ lsplit) {
  constexpr int NCH = KLEN / 32;
  __shared__ short ps_s[8][640];       // per-wave P bf16 [q][40 pad]

  const int t    = threadIdx.x;
  const int b    = blockIdx.x / 57;
  const int q0   = (blockIdx.x % 57) * 16;
  const int sp   = blockIdx.y;
  const int kb0  = sp * KLEN;
  const int w    = t >> 6;
  const int lane = t & 63;
  const int fr   = lane & 15;
  const int fk   = lane >> 4;

  int qrow = q0 + fr; if (qrow > 899) qrow = 899;
  const short8 aq = *(const short8*)&qb[(size_t)(b * 900 + qrow) * 256 +
                                        w * 32 + fk * 8];

  const short* cpbrow[4];
  #pragma unroll
  for (int r = 0; r < 4; ++r)
    cpbrow[r] = cpbg + ((size_t)(b * 8 + w) * 912 + q0 + fk * 4 + r) * 1024 + fr;

  f32x4 of[2];
  of[0] = (f32x4){0.f, 0.f, 0.f, 0.f};
  of[1] = (f32x4){0.f, 0.f, 0.f, 0.f};
  float mreg[4], lreg[4];
  #pragma unroll
  for (int r = 0; r < 4; ++r) { mreg[r] = -1e30f; lreg[r] = 0.f; }

  short8 kf0 = *(const short8*)
      &kb[(size_t)(b * 1024 + kb0 + fr) * 256 + w * 32 + fk * 8];
  short8 kf1 = *(const short8*)
      &kb[(size_t)(b * 1024 + kb0 + 16 + fr) * 256 + w * 32 + fk * 8];
  short8 bv0 = *(const short8*)
      &vT[(size_t)(b * 256 + w * 32 + fr) * 1024 + kb0 + fk * 8];
  short8 bv1 = *(const short8*)
      &vT[(size_t)(b * 256 + w * 32 + 16 + fr) * 1024 + kb0 + fk * 8];
  float cv0c[4], cv1c[4];
  #pragma unroll
  for (int r = 0; r < 4; ++r) {
    cv0c[r] = bf2f(cpbrow[r][kb0]);
    cv1c[r] = bf2f(cpbrow[r][kb0 + 16]);
  }
  bool mk0 = mask[b * 1024 + kb0 + fr] != 0;
  bool mk1 = mask[b * 1024 + kb0 + 16 + fr] != 0;

  for (int c = 0; c < NCH; ++c) {
    const int k0 = kb0 + c * 32;

    short8 kf0n = kf0, kf1n = kf1, bv0n = bv0, bv1n = bv1;
    float cv0n[4], cv1n[4];
    bool mk0n = mk0, mk1n = mk1;
    if (c + 1 < NCH) {
      const int k1 = k0 + 32;
      kf0n = *(const short8*)
          &kb[(size_t)(b * 1024 + k1 + fr) * 256 + w * 32 + fk * 8];
      kf1n = *(const short8*)
          &kb[(size_t)(b * 1024 + k1 + 16 + fr) * 256 + w * 32 + fk * 8];
      bv0n = *(const short8*)
          &vT[(size_t)(b * 256 + w * 32 + fr) * 1024 + k1 + fk * 8];
      bv1n = *(const short8*)
          &vT[(size_t)(b * 256 + w * 32 + 16 + fr) * 1024 + k1 + fk * 8];
      #pragma unroll
      for (int r = 0; r < 4; ++r) {
        cv0n[r] = bf2f(cpbrow[r][k1]);
        cv1n[r] = bf2f(cpbrow[r][k1 + 16]);
      }
      mk0n = mask[b * 1024 + k1 + fr] != 0;
      mk1n = mask[b * 1024 + k1 + 16 + fr] != 0;
    } else {
      #pragma unroll
      for (int r = 0; r < 4; ++r) { cv0n[r] = cv0c[r]; cv1n[r] = cv1c[r]; }
    }

    f32x4 z = {0.f, 0.f, 0.f, 0.f};
    __builtin_amdgcn_s_setprio(1);
    const f32x4 sc0 = __builtin_amdgcn_mfma_f32_16x16x32_bf16(aq, kf0, z, 0, 0, 0);
    const f32x4 sc1 = __builtin_amdgcn_mfma_f32_16x16x32_bf16(aq, kf1, z, 0, 0, 0);
    __builtin_amdgcn_s_setprio(0);

    float s0v[4], s1v[4];
    bool need = false;
    #pragma unroll
    for (int r = 0; r < 4; ++r) {
      s0v[r] = mk0 ? -1e30f : fmaf(sc0[r], SCALE, cv0c[r]);
      s1v[r] = mk1 ? -1e30f : fmaf(sc1[r], SCALE, cv1c[r]);
      need = need || (fmaxf(s0v[r], s1v[r]) > mreg[r] + 8.f);
    }
    if (__any((int)need)) {
      #pragma unroll
      for (int r = 0; r < 4; ++r) {
        float mx = fmaxf(s0v[r], s1v[r]);
        mx = fmaxf(mx, __shfl_xor(mx, 1));
        mx = fmaxf(mx, __shfl_xor(mx, 2));
        mx = fmaxf(mx, __shfl_xor(mx, 4));
        mx = fmaxf(mx, __shfl_xor(mx, 8));
        const float mnew = fmaxf(mreg[r], mx);
        const float al = __expf(mreg[r] - mnew);
        of[0][r] *= al;
        of[1][r] *= al;
        lreg[r] *= al;
        mreg[r] = mnew;
      }
    }
    #pragma unroll
    for (int r = 0; r < 4; ++r) {
      const int q = fk * 4 + r;
      const float p0 = __expf(s0v[r] - mreg[r]);
      const float p1 = __expf(s1v[r] - mreg[r]);
      ps_s[w][q * 40 + fr]      = f2bf(p0);
      ps_s[w][q * 40 + 16 + fr] = f2bf(p1);
      lreg[r] += p0 + p1;
    }

    asm volatile("s_waitcnt lgkmcnt(0)" ::: "memory");
    __builtin_amdgcn_sched_barrier(0);

    const short8 ap = *(const short8*)&ps_s[w][fr * 40 + fk * 8];
    __builtin_amdgcn_s_setprio(1);
    of[0] = __builtin_amdgcn_mfma_f32_16x16x32_bf16(ap, bv0, of[0], 0, 0, 0);
    of[1] = __builtin_amdgcn_mfma_f32_16x16x32_bf16(ap, bv1, of[1], 0, 0, 0);
    __builtin_amdgcn_s_setprio(0);

    kf0 = kf0n; kf1 = kf1n; bv0 = bv0n; bv1 = bv1n;
    mk0 = mk0n; mk1 = mk1n;
    #pragma unroll
    for (int r = 0; r < 4; ++r) { cv0c[r] = cv0n[r]; cv1c[r] = cv1n[r]; }
  }

  #pragma unroll
  for (int r = 0; r < 4; ++r) {
    lreg[r] += __shfl_xor(lreg[r], 1);
    lreg[r] += __shfl_xor(lreg[r], 2);
    lreg[r] += __shfl_xor(lreg[r], 4);
    lreg[r] += __shfl_xor(lreg[r], 8);
  }
  #pragma unroll
  for (int s = 0; s < 2; ++s)
    #pragma unroll
    for (int r = 0; r < 4; ++r) {
      const int qg = q0 + fk * 4 + r;
      Opart[((size_t)sp * 3648 + b * 912 + qg) * 256 + w * 32 + s * 16 + fr] =
          of[s][r];
    }
  if (fr == 0) {
    #pragma unroll
    for (int r = 0; r < 4; ++r) {
      const int qg = q0 + fk * 4 + r;
      msplit[((sp * 4 + b) * 8 + w) * 912 + qg] = mreg[r];
      lsplit[((sp * 4 + b) * 8 + w) * 912 + qg] = lreg[r];
    }
  }
}

// ---------------------------------------------------------------------------
// FALLBACK (ws too small for cpbg): fused attn (bf16 cpb LDS, 1 barrier).
// ---------------------------------------------------------------------------
#define BAR()                                              \
  asm volatile("s_waitcnt lgkmcnt(0)" ::: "memory");       \
  __builtin_amdgcn_s_barrier();                            \
  asm volatile("" ::: "memory")

template <int KLEN>
__global__ __launch_bounds__(512, 2)
void attn_part(const __hip_bfloat16* __restrict__ qb,
               const __hip_bfloat16* __restrict__ kb,
               const __hip_bfloat16* __restrict__ vT,
               const float* __restrict__ dist,
               const unsigned char* __restrict__ mask,
               const float* __restrict__ Wc1, const float* __restrict__ bc1,
               const float* __restrict__ Wc2, const float* __restrict__ bc2,
               float* __restrict__ Opart, float* __restrict__ msplit,
               float* __restrict__ lsplit) {
  constexpr int NCH = KLEN / 32;
  __shared__ short cpb_s[2][8 * 552];
  __shared__ short ps_s[8][640];

  const int t    = threadIdx.x;
  const int b    = blockIdx.x / 57;
  const int q0   = (blockIdx.x % 57) * 16;
  const int sp   = blockIdx.y;
  const int kb0  = sp * KLEN;
  const int w    = t >> 6;
  const int lane = t & 63;
  const int fr   = lane & 15;
  const int fk   = lane >> 4;

  float w1x[2][8], w1y[2][8], w1b[2][8];
  #pragma unroll
  for (int m = 0; m < 2; ++m)
    #pragma unroll
    for (int jj = 0; jj < 8; ++jj) {
      const int j = m * 32 + fk * 8 + jj;
      w1x[m][jj] = Wc1[2 * j];
      w1y[m][jj] = Wc1[2 * j + 1];
      w1b[m][jj] = bc1[j];
    }
  short8 w2f[2];
  #pragma unroll
  for (int m = 0; m < 2; ++m)
    #pragma unroll
    for (int jj = 0; jj < 8; ++jj) {
      const float v = (fr < 8) ? Wc2[fr * 64 + m * 32 + fk * 8 + jj] : 0.f;
      w2f[m][jj] = f2bf(v);
    }
  const float b2add = (fr < 8) ? bc2[fr] : 0.f;

  int qrow = q0 + fr; if (qrow > 899) qrow = 899;
  const short8 aq = *(const short8*)&qb[(size_t)(b * 900 + qrow) * 256 +
                                        w * 32 + fk * 8];

  const float* dptr[4];
  float2 d2cur[4];
  #pragma unroll
  for (int t4 = 0; t4 < 4; ++t4) {
    int qg = q0 + 2 * w + (t4 >> 1); if (qg > 899) qg = 899;
    dptr[t4] = dist +
        ((size_t)(b * 900 + qg) * 1024 + kb0 + (t4 & 1) * 16 + fr) * 2;
    d2cur[t4] = *(const float2*)dptr[t4];
  }

  f32x4 of[2];
  of[0] = (f32x4){0.f, 0.f, 0.f, 0.f};
  of[1] = (f32x4){0.f, 0.f, 0.f, 0.f};
  float mreg[4], lreg[4];
  #pragma unroll
  for (int r = 0; r < 4; ++r) { mreg[r] = -1e30f; lreg[r] = 0.f; }

  for (int c = 0; c < NCH; ++c) {
    const int k0 = kb0 + c * 32;
    const int cn = (c < NCH - 1) ? c + 1 : c;
    short* cpb_c = cpb_s[c & 1];

    float2 d2n[4];
    #pragma unroll
    for (int t4 = 0; t4 < 4; ++t4)
      d2n[t4] = *(const float2*)(dptr[t4] + (size_t)cn * 64);
    const short8 kf0 = *(const short8*)
        &kb[(size_t)(b * 1024 + k0 + fr) * 256 + w * 32 + fk * 8];
    const short8 kf1 = *(const short8*)
        &kb[(size_t)(b * 1024 + k0 + 16 + fr) * 256 + w * 32 + fk * 8];
    const short8 bv0 = *(const short8*)
        &vT[(size_t)(b * 256 + w * 32 + fr) * 1024 + k0 + fk * 8];
    const short8 bv1 = *(const short8*)
        &vT[(size_t)(b * 256 + w * 32 + 16 + fr) * 1024 + k0 + fk * 8];
    const bool mk0 = mask[b * 1024 + k0 + fr] != 0;
    const bool mk1 = mask[b * 1024 + k0 + 16 + fr] != 0;

    #pragma unroll
    for (int t4 = 0; t4 < 4; ++t4) {
      const float dx = d2cur[t4].x, dy = d2cur[t4].y;
      short8 a0, a1;
      #pragma unroll
      for (int jj = 0; jj < 8; ++jj) {
        const float h0 =
            fmaxf(fmaf(w1x[0][jj], dx, fmaf(w1y[0][jj], dy, w1b[0][jj])), 0.f);
        const float h1 =
            fmaxf(fmaf(w1x[1][jj], dx, fmaf(w1y[1][jj], dy, w1b[1][jj])), 0.f);
        a0[jj] = f2bf(h0);
        a1[jj] = f2bf(h1);
      }
      f32x4 z = {0.f, 0.f, 0.f, 0.f};
      f32x4 dcp = __builtin_amdgcn_mfma_f32_16x16x32_bf16(a1, w2f[1], z, 0, 0, 0);
      dcp = __builtin_amdgcn_mfma_f32_16x16x32_bf16(a0, w2f[0], dcp, 0, 0, 0);
      const int qloc = 2 * w + (t4 >> 1);
      const int kbase = (t4 & 1) * 16;
      if (fr < 8) {
        #pragma unroll
        for (int rr = 0; rr < 4; ++rr)
          cpb_c[fr * 552 + qloc * 34 + kbase + fk * 4 + rr] =
              f2bf(dcp[rr] + b2add);
      }
      __builtin_amdgcn_sched_barrier(0);
    }

    BAR();

    f32x4 z = {0.f, 0.f, 0.f, 0.f};
    __builtin_amdgcn_s_setprio(1);
    const f32x4 sc0 = __builtin_amdgcn_mfma_f32_16x16x32_bf16(aq, kf0, z, 0, 0, 0);
    const f32x4 sc1 = __builtin_amdgcn_mfma_f32_16x16x32_bf16(aq, kf1, z, 0, 0, 0);
    __builtin_amdgcn_s_setprio(0);

    float s0v[4], s1v[4];
    bool need = false;
    #pragma unroll
    for (int r = 0; r < 4; ++r) {
      const int q = fk * 4 + r;
      const float cv0 = bf2f(cpb_c[w * 552 + q * 34 + fr]);
      const float cv1 = bf2f(cpb_c[w * 552 + q * 34 + 16 + fr]);
      s0v[r] = mk0 ? -1e30f : fmaf(sc0[r], SCALE, cv0);
      s1v[r] = mk1 ? -1e30f : fmaf(sc1[r], SCALE, cv1);
      need = need || (fmaxf(s0v[r], s1v[r]) > mreg[r] + 8.f);
    }
    if (__any((int)need)) {
      #pragma unroll
      for (int r = 0; r < 4; ++r) {
        float mx = fmaxf(s0v[r], s1v[r]);
        mx = fmaxf(mx, __shfl_xor(mx, 1));
        mx = fmaxf(mx, __shfl_xor(mx, 2));
        mx = fmaxf(mx, __shfl_xor(mx, 4));
        mx = fmaxf(mx, __shfl_xor(mx, 8));
        const float mnew = fmaxf(mreg[r], mx);
        const float al = __expf(mreg[r] - mnew);
        of[0][r] *= al;
        of[1][r] *= al;
        lreg[r] *= al;
        mreg[r] = mnew;
      }
    }
    #pragma unroll
    for (int r = 0; r < 4; ++r) {
      const int q = fk * 4 + r;
      const float p0 = __expf(s0v[r] - mreg[r]);
      const float p1 = __expf(s1v[r] - mreg[r]);
      ps_s[w][q * 40 + fr]      = f2bf(p0);
      ps_s[w][q * 40 + 16 + fr] = f2bf(p1);
      lreg[r] += p0 + p1;
    }

    asm volatile("s_waitcnt lgkmcnt(0)" ::: "memory");
    __builtin_amdgcn_sched_barrier(0);

    const short8 ap = *(const short8*)&ps_s[w][fr * 40 + fk * 8];
    __builtin_amdgcn_s_setprio(1);
    of[0] = __builtin_amdgcn_mfma_f32_16x16x32_bf16(ap, bv0, of[0], 0, 0, 0);
    of[1] = __builtin_amdgcn_mfma_f32_16x16x32_bf16(ap, bv1, of[1], 0, 0, 0);
    __builtin_amdgcn_s_setprio(0);

    #pragma unroll
    for (int t4 = 0; t4 < 4; ++t4) d2cur[t4] = d2n[t4];
  }

  #pragma unroll
  for (int r = 0; r < 4; ++r) {
    lreg[r] += __shfl_xor(lreg[r], 1);
    lreg[r] += __shfl_xor(lreg[r], 2);
    lreg[r] += __shfl_xor(lreg[r], 4);
    lreg[r] += __shfl_xor(lreg[r], 8);
  }
  #pragma unroll
  for (int s = 0; s < 2; ++s)
    #pragma unroll
    for (int r = 0; r < 4; ++r) {
      const int qg = q0 + fk * 4 + r;
      Opart[((size_t)sp * 3648 + b * 912 + qg) * 256 + w * 32 + s * 16 + fr] =
          of[s][r];
    }
  if (fr == 0) {
    #pragma unroll
    for (int r = 0; r < 4; ++r) {
      const int qg = q0 + fk * 4 + r;
      msplit[((sp * 4 + b) * 8 + w) * 912 + qg] = mreg[r];
      lsplit[((sp * 4 + b) * 8 + w) * 912 + qg] = lreg[r];
    }
  }
}

// ---------------------------------------------------------------------------
// Fused combine + out-proj (f16 MFMA; wob pre-cast to f16).
// ---------------------------------------------------------------------------
template <int NS>
__global__ __launch_bounds__(256, 4)
void gemm_out_combine(const float* __restrict__ Opart,
                      const float* __restrict__ msplit,
                      const float* __restrict__ lsplit,
                      const short* __restrict__ wob, const float* __restrict__ bo,
                      float* __restrict__ out) {
  const int t = threadIdx.x, w = t >> 6, lane = t & 63;
  const int fr = lane & 15, fk = lane >> 4;
  const int m0 = (blockIdx.x >> 2) * 64, n0 = (blockIdx.x & 3) * 64;
  int arow = m0 + w * 16 + fr; if (arow > 3599) arow = 3599;
  const int b = arow / 900, q = arow - b * 900;
  const int row912 = b * 912 + q;
  f32x4 acc[4];
  #pragma unroll
  for (int s = 0; s < 4; ++s) acc[s] = (f32x4){0.f, 0.f, 0.f, 0.f};
  #pragma unroll 2
  for (int k0 = 0; k0 < 256; k0 += 32) {
    const int h = k0 >> 5;
    float mv[NS], M = -1e30f;
    #pragma unroll
    for (int s = 0; s < NS; ++s) {
      mv[s] = msplit[((s * 4 + b) * 8 + h) * 912 + q];
      M = fmaxf(M, mv[s]);
    }
    float L = 0.f, wgt[NS];
    #pragma unroll
    for (int s = 0; s < NS; ++s) {
      wgt[s] = __expf(mv[s] - M);
      L = fmaf(lsplit[((s * 4 + b) * 8 + h) * 912 + q], wgt[s], L);
    }
    const float rL = 1.f / L;
    float av[8];
    #pragma unroll
    for (int j = 0; j < 8; ++j) av[j] = 0.f;
    #pragma unroll
    for (int s = 0; s < NS; ++s) {
      const float* op = &Opart[((size_t)s * 3648 + row912) * 256 + k0 + fk * 8];
      const float4 o0 = *(const float4*)op;
      const float4 o1 = *(const float4*)(op + 4);
      const float ws = wgt[s] * rL;
      av[0] = fmaf(o0.x, ws, av[0]); av[1] = fmaf(o0.y, ws, av[1]);
      av[2] = fmaf(o0.z, ws, av[2]); av[3] = fmaf(o0.w, ws, av[3]);
      av[4] = fmaf(o1.x, ws, av[4]); av[5] = fmaf(o1.y, ws, av[5]);
      av[6] = fmaf(o1.z, ws, av[6]); av[7] = fmaf(o1.w, ws, av[7]);
    }
    half8 af;
    #pragma unroll
    for (int j = 0; j < 8; ++j) af[j] = (_Float16)av[j];
    #pragma unroll
    for (int s = 0; s < 4; ++s) {
      union { short8 s8; half8 h8; } wf;
      wf.s8 = *(const short8*)&wob[(size_t)(n0 + s * 16 + fr) * 256 + k0 + fk * 8];
      acc[s] = __builtin_amdgcn_mfma_f32_16x16x32_f16(af, wf.h8, acc[s], 0, 0, 0);
    }
  }
  #pragma unroll
  for (int s = 0; s < 4; ++s)
    #pragma unroll
    for (int r = 0; r < 4; ++r) {
      const int m = m0 + w * 16 + fk * 4 + r;
      const int n = n0 + s * 16 + fr;
      if (m < 3600) out[(size_t)m * 256 + n] = acc[s][r] + bo[n];
    }
}

// ---------------------------------------------------------------------------
extern "C" void kernel_launch(void* const* d_in, const int* in_sizes, int n_in,
                              void* d_out, int out_size, void* d_ws, size_t ws_size,
                              hipStream_t stream) {
  const float* nodes  = (const float*)d_in[0];
  const float* images = (const float*)d_in[1];
  const unsigned char* mask = (const unsigned char*)d_in[2];
  const float* dist   = (const float*)d_in[3];
  const float* Wq     = (const float*)d_in[4];
  const float* bq     = (const float*)d_in[5];
  const float* Wkv    = (const float*)d_in[6];
  const float* bkv    = (const float*)d_in[7];
  const float* Wc1    = (const float*)d_in[8];
  const float* bc1    = (const float*)d_in[9];
  const float* Wc2    = (const float*)d_in[10];
  const float* bc2    = (const float*)d_in[11];
  const float* Wo     = (const float*)d_in[12];
  const float* bo     = (const float*)d_in[13];
  float* out = (float*)d_out;

  char* wp = (char*)d_ws;
  short* qb = (short*)wp;                       // 1,843,200
  short* kb = (short*)(wp + 1843200);           // 2,097,152
  short* vT = (short*)(wp + 3940352);           // 2,097,152
  char*  S  = wp + 6037504;
  short* nb   = (short*)S;
  short* ib   = (short*)(S + 1843200);
  short* wqb  = (short*)(S + 3940352);
  short* wkvb = (short*)(S + 4071424);          // phase1 ends 4,333,568
  float* Opart = (float*)S;

  const size_t opart_b = (size_t)3648 * 256 * 4;      // 3,735,552
  const size_t ml_b    = (size_t)4 * 8 * 912 * 4;     //   116,736
  const size_t s2_2    = 2 * (opart_b + 2 * ml_b);    // 7,938,048
  const size_t cpbg_sz = (size_t)4 * 8 * 912 * 1024 * 2;  // 59,768,832
  const size_t need_big = 6037504u + s2_2 + cpbg_sz + 131072u;
  const size_t need2    = 6037504u + s2_2 + 131072u;

  if (ws_size >= need_big) {
    short* cpbg = (short*)(S + s2_2);
    short* wob  = (short*)(S + s2_2 + cpbg_sz);
    float* msplit = Opart + (size_t)2 * 3648 * 256;
    float* lsplit = msplit + (size_t)2 * 4 * 8 * 912;
    cvt_bf16<<<1090, 256, 0, stream>>>(nodes, images, Wq, Wkv, Wo,
                                       nb, ib, wqb, wkvb, wob);
    gemm_cpb<<<2564, 256, 0, stream>>>(nb, wqb, bq, qb, ib, wkvb, bkv, kb, vT,
                                       dist, Wc1, bc1, Wc2, bc2, cpbg);
    attn_nb<512><<<dim3(228, 2), 512, 0, stream>>>(
        (const __hip_bfloat16*)qb, (const __hip_bfloat16*)kb,
        (const __hip_bfloat16*)vT, cpbg, mask, Opart, msplit, lsplit);
    gemm_out_combine<2><<<228, 256, 0, stream>>>(Opart, msplit, lsplit,
                                                 wob, bo, out);
  } else {
    int nsplit = (ws_size >= need2) ? 2 : 1;
    const size_t Ssize = (nsplit == 2) ? s2_2 : 4333568u;
    short* wob = (short*)(S + Ssize);
    float* msplit = Opart + (size_t)nsplit * 3648 * 256;
    float* lsplit = msplit + (size_t)nsplit * 4 * 8 * 912;
    cvt_bf16<<<1090, 256, 0, stream>>>(nodes, images, Wq, Wkv, Wo,
                                       nb, ib, wqb, wkvb, wob);
    gemm_qkv_mfma<<<740, 256, 0, stream>>>(nb, wqb, bq, qb, ib, wkvb, bkv,
                                           kb, vT);
    if (nsplit == 2) {
      attn_part<512><<<dim3(228, 2), 512, 0, stream>>>(
          (const __hip_bfloat16*)qb, (const __hip_bfloat16*)kb,
          (const __hip_bfloat16*)vT, dist, mask, Wc1, bc1, Wc2, bc2,
          Opart, msplit, lsplit);
      gemm_out_combine<2><<<228, 256, 0, stream>>>(Opart, msplit, lsplit,
                                                   wob, bo, out);
    } else {
      attn_part<1024><<<dim3(228, 1), 512, 0, stream>>>(
          (const __hip_bfloat16*)qb, (const __hip_bfloat16*)kb,
          (const __hip_bfloat16*)vT, dist, mask, Wc1, bc1, Wc2, bc2,
          Opart, msplit, lsplit);
      gemm_out_combine<1><<<228, 256, 0, stream>>>(Opart, msplit, lsplit,
                                                   wob, bo, out);
    }
  }
}